// Round 1
// baseline (4240.015 us; speedup 1.0000x reference)
//
#include <hip/hip_runtime.h>

// ---------------------------------------------------------------------------
// DrugGCN: 2-layer GCN (PyG GCNConv semantics) + ReLU + column mean.
//   deg[i]   = 1 + indegree(i);  dinv = rsqrt(deg)
//   h        = A @ W
//   agg[i]   = h[i]*dinv[i]^2 + b  (self-loop + bias)
//   agg[d]  += h[s]*dinv[s]*dinv[d]   for each edge (s,d)   [atomicAdd]
//   layer2 input = relu(agg1), final out = mean_i relu(agg2[i])  [256]
// ---------------------------------------------------------------------------

union F4 { float4 v; float f[4]; };

// --- edge-index dtype detection (int32 vs int64 in device buffer) ----------
// If the buffer holds int64 little-endian indices (< 2^31), every odd 32-bit
// word of the first 2*E ints is 0. If it holds int32 src/dst, odd words are
// random node ids -> OR is nonzero with overwhelming probability.
__global__ void k_or_odd(const int* __restrict__ ei, int n_pairs, int* flag) {
    int i = blockIdx.x * 256 + threadIdx.x;
    int v = (i < n_pairs) ? ei[2 * i + 1] : 0;
    unsigned long long m = __ballot(v != 0);
    if ((threadIdx.x & 63) == 0 && m != 0ull) atomicOr(flag, 1);
}

__device__ __forceinline__ int edge_idx(const void* ei, int is64, int which,
                                        int E, int e) {
    if (is64) return (int)((const long long*)ei)[(size_t)which * E + e];
    return ((const int*)ei)[(size_t)which * E + e];
}

// --- degree / dinv ----------------------------------------------------------
__global__ void k_fill1(float* p, int n) {
    int i = blockIdx.x * 256 + threadIdx.x;
    if (i < n) p[i] = 1.0f;
}

__global__ void k_count(const void* __restrict__ ei, const int* __restrict__ flag,
                        float* deg, int E) {
    int e = blockIdx.x * 256 + threadIdx.x;
    if (e >= E) return;
    int is64 = (*flag == 0);
    int d = edge_idx(ei, is64, 1, E, e);
    atomicAdd(&deg[d], 1.0f);
}

__global__ void k_rsqrt(float* p, int n) {
    int i = blockIdx.x * 256 + threadIdx.x;
    if (i < n) p[i] = rsqrtf(p[i]);
}

// --- GEMM: C[N,K] = A[N,128] @ W[128,K], optional relu on A load ------------
// block = 256 threads, computes 64 rows x K cols in 64-col tiles.
// LDS: xs 64x128 f32 (32KB) + ws 128x64 f32 (32KB) = 64KB exactly.
template <int K, bool RELU_IN>
__global__ __launch_bounds__(256) void k_gemm(const float* __restrict__ A,
                                              const float* __restrict__ W,
                                              float* __restrict__ C, int N) {
    __shared__ float xs[64 * 128];
    __shared__ float ws[128 * 64];
    const int tid = threadIdx.x;
    const int row0 = blockIdx.x * 64;

    // stage x tile (64x128), float4 loads, zero-pad OOB rows
#pragma unroll
    for (int i = 0; i < 8; ++i) {
        int idx = tid + i * 256;        // float4 index, 2048 total
        int r = idx >> 5;               // 32 float4 per row
        int c4 = idx & 31;
        float4 v = make_float4(0.f, 0.f, 0.f, 0.f);
        if (row0 + r < N) {
            v = reinterpret_cast<const float4*>(A + (size_t)(row0 + r) * 128)[c4];
            if (RELU_IN) {
                v.x = fmaxf(v.x, 0.f); v.y = fmaxf(v.y, 0.f);
                v.z = fmaxf(v.z, 0.f); v.w = fmaxf(v.w, 0.f);
            }
        }
        reinterpret_cast<float4*>(xs)[idx] = v;
    }

    const int tx = tid & 15, ty = tid >> 4;
    const int r0 = ty * 4, c0 = tx * 4;

#pragma unroll
    for (int ct = 0; ct < K / 64; ++ct) {
        __syncthreads();   // xs ready (iter 0) / prev compute done with ws
        // stage W tile (128x64)
#pragma unroll
        for (int i = 0; i < 8; ++i) {
            int idx = tid + i * 256;    // float4 index over 128*16
            int k = idx >> 4, c4 = idx & 15;
            reinterpret_cast<float4*>(ws)[idx] =
                reinterpret_cast<const float4*>(W + (size_t)k * K + ct * 64)[c4];
        }
        __syncthreads();

        float acc[4][4] = {};
#pragma unroll
        for (int k4 = 0; k4 < 32; ++k4) {
            F4 xr[4], wr[4];
#pragma unroll
            for (int i = 0; i < 4; ++i)
                xr[i].v = *reinterpret_cast<const float4*>(&xs[(r0 + i) * 128 + k4 * 4]);
#pragma unroll
            for (int kk = 0; kk < 4; ++kk)
                wr[kk].v = *reinterpret_cast<const float4*>(&ws[(k4 * 4 + kk) * 64 + c0]);
#pragma unroll
            for (int i = 0; i < 4; ++i)
#pragma unroll
                for (int kk = 0; kk < 4; ++kk) {
                    float xv = xr[i].f[kk];
#pragma unroll
                    for (int j = 0; j < 4; ++j)
                        acc[i][j] = fmaf(xv, wr[kk].f[j], acc[i][j]);
                }
        }

#pragma unroll
        for (int i = 0; i < 4; ++i) {
            int r = row0 + r0 + i;
            if (r < N) {
                float4 o = make_float4(acc[i][0], acc[i][1], acc[i][2], acc[i][3]);
                *reinterpret_cast<float4*>(&C[(size_t)r * K + ct * 64 + c0]) = o;
            }
        }
    }
}

// --- self-loop + bias init: agg = h * dinv[row]^2 + b -----------------------
template <int F>
__global__ void k_self(const float* __restrict__ h, const float* __restrict__ dinv,
                       const float* __restrict__ bias, float* __restrict__ agg,
                       int n4) {
    int idx = blockIdx.x * 256 + threadIdx.x;
    if (idx >= n4) return;
    constexpr int F4 = F / 4;
    int row = idx / F4;
    int c4 = idx % F4;
    float s = dinv[row];
    s *= s;
    float4 v = reinterpret_cast<const float4*>(h)[idx];
    float4 b = reinterpret_cast<const float4*>(bias)[c4];
    float4 o = make_float4(fmaf(v.x, s, b.x), fmaf(v.y, s, b.y),
                           fmaf(v.z, s, b.z), fmaf(v.w, s, b.w));
    reinterpret_cast<float4*>(agg)[idx] = o;
}

// --- edge scatter: agg[d] += h[s] * dinv[s]*dinv[d]  (wave per edge) --------
template <int F>
__global__ void k_scatter(const void* __restrict__ ei, const int* __restrict__ flag,
                          const float* __restrict__ h, const float* __restrict__ dinv,
                          float* __restrict__ agg, int E) {
    int e = blockIdx.x * 4 + (threadIdx.x >> 6);
    if (e >= E) return;
    int lane = threadIdx.x & 63;
    int is64 = (*flag == 0);
    int s = edge_idx(ei, is64, 0, E, e);
    int d = edge_idx(ei, is64, 1, E, e);
    float w = dinv[s] * dinv[d];
    const float* hs = h + (size_t)s * F;
    float* ad = agg + (size_t)d * F;
#pragma unroll
    for (int f = 0; f < F; f += 64)
        atomicAdd(&ad[f + lane], hs[f + lane] * w);
}

// --- final: out[t] = (1/N) sum_i relu(agg[i][t]),  t in [0,256) -------------
__global__ void k_mean(const float* __restrict__ agg, float* __restrict__ out,
                       int N, float invN) {
    int t = threadIdx.x;  // 256 threads = 256 columns
    float sum = 0.f;
    for (int r = blockIdx.x; r < N; r += gridDim.x)
        sum += fmaxf(agg[(size_t)r * 256 + t], 0.f);
    atomicAdd(&out[t], sum * invN);
}

// ---------------------------------------------------------------------------
extern "C" void kernel_launch(void* const* d_in, const int* in_sizes, int n_in,
                              void* d_out, int out_size, void* d_ws, size_t ws_size,
                              hipStream_t stream) {
    const float* x  = (const float*)d_in[0];
    const void*  ei = d_in[1];
    const float* W1 = (const float*)d_in[2];
    const float* b1 = (const float*)d_in[3];
    const float* W2 = (const float*)d_in[4];
    const float* b2 = (const float*)d_in[5];
    float* out = (float*)d_out;

    const int N = in_sizes[0] / 128;   // 100000
    const int E = in_sizes[1] / 2;     // 600000

    // workspace layout (all 256B aligned):
    //   [flag 256B][dinv N*4][h1 N*128*4][agg1 N*128*4][h2 N*256*4]
    //   agg2 aliases [h1;agg1] (dead by then, exactly N*256*4 bytes)
    char* ws = (char*)d_ws;
    int*   flag = (int*)ws;
    size_t off = 256;
    float* dinv = (float*)(ws + off);
    off += ((size_t)N * 4 + 255) & ~(size_t)255;
    float* h1 = (float*)(ws + off);
    float* agg2 = h1;
    off += (size_t)N * 128 * 4;
    float* agg1 = (float*)(ws + off);
    off += (size_t)N * 128 * 4;
    float* h2 = (float*)(ws + off);

    // --- edge dtype detection + degrees ---
    hipMemsetAsync(flag, 0, sizeof(int), stream);
    k_or_odd<<<(E + 255) / 256, 256, 0, stream>>>((const int*)ei, E, flag);
    k_fill1<<<(N + 255) / 256, 256, 0, stream>>>(dinv, N);
    k_count<<<(E + 255) / 256, 256, 0, stream>>>(ei, flag, dinv, E);
    k_rsqrt<<<(N + 255) / 256, 256, 0, stream>>>(dinv, N);

    // --- layer 1: h1 = x@W1; agg1 = scatter(h1)+self+b1 ---
    k_gemm<128, false><<<(N + 63) / 64, 256, 0, stream>>>(x, W1, h1, N);
    k_self<128><<<(N * 32 + 255) / 256, 256, 0, stream>>>(h1, dinv, b1, agg1, N * 32);
    k_scatter<128><<<(E + 3) / 4, 256, 0, stream>>>(ei, flag, h1, dinv, agg1, E);

    // --- layer 2: h2 = relu(agg1)@W2; agg2 = scatter(h2)+self+b2 ---
    k_gemm<256, true><<<(N + 63) / 64, 256, 0, stream>>>(agg1, W2, h2, N);
    k_self<256><<<(N * 64 + 255) / 256, 256, 0, stream>>>(h2, dinv, b2, agg2, N * 64);
    k_scatter<256><<<(E + 3) / 4, 256, 0, stream>>>(ei, flag, h2, dinv, agg2, E);

    // --- final mean of relu ---
    hipMemsetAsync(d_out, 0, (size_t)out_size * sizeof(float), stream);
    k_mean<<<512, 256, 0, stream>>>(agg2, out, N, 1.0f / (float)N);
}